// Round 4
// baseline (1753.967 us; speedup 1.0000x reference)
//
#include <hip/hip_runtime.h>
#include <math.h>

#define DIM   1024
#define HID   2048
#define NEXP  8
#define MTOK  16384      // 4*4096 tokens
#define NSLOT 32768      // MTOK * top2

// header layout (ints) at ws+0
#define H_COUNT 0        // counts[8]
#define H_OFFS  8        // offsets[9]
#define H_CUR   24       // cursors[8]
#define H_TILES 40       // tiles[8] = ceil(count/128)

#define GRID4 8416       // 8 * CAP4 ; >= max sum tiles*32 (=263*32)
#define CAP4  1052
#define GRID5 2104       // 8 * CAP5 ; >= max sum tiles*8
#define CAP5  263

typedef unsigned short ushort_t;
typedef unsigned int u32;
typedef __bf16 bf16x8 __attribute__((ext_vector_type(8)));
typedef float floatx4 __attribute__((ext_vector_type(4)));

__device__ __forceinline__ unsigned short f2bf(float f) {
  union { float f; unsigned int i; } z; z.f = f;
  unsigned int r = z.i + 0x7fffu + ((z.i >> 16) & 1u);
  return (unsigned short)(r >> 16);
}

// async global->LDS, 16B per lane. LDS dest = wave-uniform base + lane*16.
__device__ __forceinline__ void gld16(const ushort_t* g, ushort_t* l) {
  __builtin_amdgcn_global_load_lds(
      (const __attribute__((address_space(1))) u32*)g,
      (__attribute__((address_space(3))) u32*)l, 16, 0, 0);
}

__global__ void k0_init(int* hdr) {
  int t = threadIdx.x;
  if (t < 64) hdr[t] = 0;
}

// fp32 -> bf16 conversion (grid-stride over float4s)
__global__ __launch_bounds__(256) void kconv(
    const float* __restrict__ src, ushort_t* __restrict__ dst, int n4)
{
  int i = blockIdx.x * 256 + threadIdx.x;
  int stride = gridDim.x * 256;
  for (; i < n4; i += stride) {
    float4 v = ((const float4*)src)[i];
    ushort4 o; o.x = f2bf(v.x); o.y = f2bf(v.y); o.z = f2bf(v.z); o.w = f2bf(v.w);
    ((ushort4*)dst)[i] = o;
  }
}

// RMSNorm + router + top2 + softmax. One block (256 thr)/token.
__global__ __launch_bounds__(256) void k1_norm_router(
    const float* __restrict__ x, const float* __restrict__ scale,
    const float* __restrict__ wr, ushort_t* __restrict__ xn,
    int* __restrict__ ids, float* __restrict__ wts, int* __restrict__ hdr)
{
  int token = blockIdx.x, t = threadIdx.x;
  int lane = t & 63, wid = t >> 6;

  float4 xv = ((const float4*)(x + (size_t)token * DIM))[t];
  double ss = (double)xv.x*xv.x + (double)xv.y*xv.y
            + (double)xv.z*xv.z + (double)xv.w*xv.w;
  #pragma unroll
  for (int o = 32; o; o >>= 1) ss += __shfl_down(ss, o, 64);

  __shared__ double sred[4];
  __shared__ float sbc;
  if (lane == 0) sred[wid] = ss;
  __syncthreads();
  if (t == 0) {
    double ms = (sred[0] + sred[1] + sred[2] + sred[3]) * (1.0 / (double)DIM);
    sbc = (float)(1.0 / sqrt(ms + 1e-6));
  }
  __syncthreads();
  float s = sbc;
  float4 sv = ((const float4*)scale)[t];
  float n0f = xv.x * s * sv.x, n1f = xv.y * s * sv.y;
  float n2f = xv.z * s * sv.z, n3f = xv.w * s * sv.w;
  ushort4 xo; xo.x = f2bf(n0f); xo.y = f2bf(n1f); xo.z = f2bf(n2f); xo.w = f2bf(n3f);
  ((ushort4*)(xn + (size_t)token * DIM))[t] = xo;

  double p[NEXP];
  #pragma unroll
  for (int e = 0; e < NEXP; e++) {
    float4 wv = ((const float4*)(wr + e * DIM))[t];
    p[e] = (double)n0f * wv.x + (double)n1f * wv.y
         + (double)n2f * wv.z + (double)n3f * wv.w;
  }
  #pragma unroll
  for (int e = 0; e < NEXP; e++) {
    double v = p[e];
    #pragma unroll
    for (int o = 32; o; o >>= 1) v += __shfl_down(v, o, 64);
    p[e] = v;
  }
  __shared__ double pr[4][NEXP];
  if (lane == 0) {
    #pragma unroll
    for (int e = 0; e < NEXP; e++) pr[wid][e] = p[e];
  }
  __syncthreads();
  if (t == 0) {
    double sc[NEXP];
    #pragma unroll
    for (int e = 0; e < NEXP; e++) sc[e] = pr[0][e] + pr[1][e] + pr[2][e] + pr[3][e];
    int e0 = 0;
    for (int e = 1; e < NEXP; e++) if (sc[e] > sc[e0]) e0 = e;
    int e1 = (e0 == 0) ? 1 : 0;
    for (int e = 0; e < NEXP; e++) if (e != e0 && sc[e] > sc[e1]) e1 = e;
    double d = exp(sc[e1] - sc[e0]);
    float w0 = (float)(1.0 / (1.0 + d));
    float w1 = (float)(d / (1.0 + d));
    ids[2 * token] = e0; ids[2 * token + 1] = e1;
    wts[2 * token] = w0; wts[2 * token + 1] = w1;
    atomicAdd(&hdr[H_COUNT + e0], 1);
    atomicAdd(&hdr[H_COUNT + e1], 1);
  }
}

__global__ void k2_scan(int* hdr) {
  if (threadIdx.x == 0 && blockIdx.x == 0) {
    int off = 0;
    for (int e = 0; e < NEXP; e++) {
      hdr[H_OFFS + e] = off; off += hdr[H_COUNT + e];
      hdr[H_TILES + e] = (hdr[H_COUNT + e] + 127) >> 7;
    }
    hdr[H_OFFS + NEXP] = off;
  }
}

__global__ __launch_bounds__(256) void k3_scatter(
    const int* __restrict__ ids, int* __restrict__ hdr, int* __restrict__ perm)
{
  int s = blockIdx.x * 256 + threadIdx.x;
  if (s < NSLOT) {
    int e = ids[s];
    int pos = atomicAdd(&hdr[H_CUR + e], 1);
    perm[hdr[H_OFFS + e] + pos] = s;
  }
}

// ---- XCD-affine work decode ----
// k4: XCD x owns units u=x and u=x+8, where unit u=(e*2+h): expert e=u>>1,
// col-half h=u&1 (16 colchunks each, B-slab 4MB). cc-fastest within tile.
__device__ __forceinline__ bool dec4(int x, int j, const int* tiles,
                                     int& e, int& t, int& cc) {
  int eA = x >> 1, h = x & 1;
  int nA = tiles[eA] << 4;
  if (j < nA) { e = eA; t = j >> 4; cc = (h << 4) | (j & 15); return true; }
  j -= nA;
  int eB = eA + 4;
  int nB = tiles[eB] << 4;
  if (j < nB) { e = eB; t = j >> 4; cc = (h << 4) | (j & 15); return true; }
  return false;
}
// k5: XCD x owns expert x (B_e = 4MB). 8 colchunks per tile, cc-fastest.
__device__ __forceinline__ bool dec5(int x, int j, const int* tiles,
                                     int& e, int& t, int& cc) {
  int n = tiles[x] << 3;
  if (j < n) { e = x; t = j >> 3; cc = j & 7; return true; }
  return false;
}

// grouped GEMM: up + SwiGLU. Block tile 128 rows x 128 B-rows (64 u + 64 gate
// interleaved per 32), K=1024. LDS layout [kseg][row][16B], conflict-free.
__global__ __launch_bounds__(256) void k4_up(
    const ushort_t* __restrict__ xn, const ushort_t* __restrict__ wup,
    const int* __restrict__ hdr, const int* __restrict__ perm,
    ushort_t* __restrict__ h)
{
  const int* tiles = hdr + H_TILES;
  int id = blockIdx.x, x = id & 7, j = id >> 3;
  int e, t, cc;
  if (!dec4(x, j, tiles, e, t, cc)) {
    int d[8];
    #pragma unroll
    for (int q = 0; q < 8; q++) d[q] = (tiles[q >> 1] + tiles[(q >> 1) + 4]) << 4;
    int spare = j - d[x];
    for (int q = 0; q < x; q++) { int s = CAP4 - d[q]; if (s > 0) spare += s; }
    bool found = false;
    for (int xs = 0; xs < 8; xs++) {
      int ov = d[xs] - CAP4;
      if (ov <= 0) continue;
      if (spare < ov) { dec4(xs, CAP4 + spare, tiles, e, t, cc); found = true; break; }
      spare -= ov;
    }
    if (!found) return;
  }
  int row0 = hdr[H_OFFS + e] + (t << 7);
  int nrows = hdr[H_OFFS + e + 1] - row0; if (nrows > 128) nrows = 128;
  int n0 = cc << 6;   // h-col base (0..2047 step 64)

  __shared__ __align__(16) ushort_t As[4096];  // [4 kseg][128 row][8 bf16]
  __shared__ __align__(16) ushort_t Bs[4096];
  __shared__ int rowslot[128];

  int tt = threadIdx.x;
  if (tt < 128) rowslot[tt] = (tt < nrows) ? perm[row0 + tt] : -1;

  int lane = tt & 63, wave = tt >> 6;
  const ushort_t* wbase = wup + (size_t)e * 4096 * DIM;

  // staging: waves 0,1 -> A (segs 0,1 / 2,3); waves 2,3 -> B
  const ushort_t *gpL, *gpH; ushort_t* lb;
  int sp = (wave & 1) << 1;   // seg-pair base
  if (wave < 2) {
    int rL = (lane < nrows) ? lane : 0;
    int rH = (64 + lane < nrows) ? 64 + lane : 0;
    int tokL = perm[row0 + rL] >> 1;
    int tokH = perm[row0 + rH] >> 1;
    gpL = xn + (size_t)tokL * DIM;
    gpH = xn + (size_t)tokH * DIM;
    lb = As;
  } else {
    // col c: (c&63)<32 -> u row n0+(c>>6)*32+(c&31); else gate row 2048+...
    int gr0 = (lane < 32) ? (n0 + lane) : (2048 + n0 + lane - 32);
    int gr1 = (lane < 32) ? (n0 + 32 + lane) : (2048 + n0 + lane);
    gpL = wbase + (size_t)gr0 * DIM;
    gpH = wbase + (size_t)gr1 * DIM;
    lb = Bs;
  }

  floatx4 acc[4][4];
  #pragma unroll
  for (int a = 0; a < 4; a++)
  #pragma unroll
  for (int b = 0; b < 4; b++) acc[a][b] = (floatx4){0.f, 0.f, 0.f, 0.f};

  int quad = lane >> 4, l15 = lane & 15;
  int wr64 = (wave >> 1) << 6;   // wave row-half
  int wc = wave & 1;             // wave col-half
  int abyte = quad * 2048 + (wr64 + l15) * 16;
  int bbyte = quad * 2048 + ((wc << 6) + l15) * 16;

  for (int kb = 0; kb < DIM / 32; ++kb) {
    gld16(gpL + sp * 8,     lb + sp * 1024);
    gld16(gpL + sp * 8 + 8, lb + sp * 1024 + 1024);
    gld16(gpH + sp * 8,     lb + sp * 1024 + 512);
    gld16(gpH + sp * 8 + 8, lb + sp * 1024 + 1536);
    gpL += 32; gpH += 32;
    __syncthreads();
    bf16x8 af0 = *(const bf16x8*)((const char*)As + abyte);
    bf16x8 af1 = *(const bf16x8*)((const char*)As + abyte + 256);
    bf16x8 af2 = *(const bf16x8*)((const char*)As + abyte + 512);
    bf16x8 af3 = *(const bf16x8*)((const char*)As + abyte + 768);
    #pragma unroll
    for (int ct = 0; ct < 4; ++ct) {
      bf16x8 bfr = *(const bf16x8*)((const char*)Bs + bbyte + ct * 256);
      acc[0][ct] = __builtin_amdgcn_mfma_f32_16x16x32_bf16(af0, bfr, acc[0][ct], 0, 0, 0);
      acc[1][ct] = __builtin_amdgcn_mfma_f32_16x16x32_bf16(af1, bfr, acc[1][ct], 0, 0, 0);
      acc[2][ct] = __builtin_amdgcn_mfma_f32_16x16x32_bf16(af2, bfr, acc[2][ct], 0, 0, 0);
      acc[3][ct] = __builtin_amdgcn_mfma_f32_16x16x32_bf16(af3, bfr, acc[3][ct], 0, 0, 0);
    }
    __syncthreads();
  }

  // SwiGLU: within wave's 64 cols, ct 0,1 = u, ct 2,3 = matching gate
  #pragma unroll
  for (int rt = 0; rt < 4; ++rt)
  #pragma unroll
  for (int cu = 0; cu < 2; ++cu) {
    floatx4 u = acc[rt][cu];
    floatx4 g = acc[rt][cu + 2];
    #pragma unroll
    for (int jj = 0; jj < 4; ++jj) {
      int r = wr64 + rt * 16 + quad * 4 + jj;
      int slot = rowslot[r];
      if (slot >= 0) {
        float gv = g[jj];
        float hv = u[jj] * (gv / (1.0f + expf(-gv)));
        h[(size_t)slot * HID + n0 + wc * 32 + cu * 16 + l15] = f2bf(hv);
      }
    }
  }
}

// grouped GEMM: down, weighted -> bf16 dwn. Block 128 rows x 128 cols, K=2048.
__global__ __launch_bounds__(256) void k5_down(
    const ushort_t* __restrict__ h, const ushort_t* __restrict__ wdn,
    const int* __restrict__ hdr, const int* __restrict__ perm,
    const float* __restrict__ wts, ushort_t* __restrict__ dwn)
{
  const int* tiles = hdr + H_TILES;
  int id = blockIdx.x, x = id & 7, j = id >> 3;
  int e, t, cc;
  if (!dec5(x, j, tiles, e, t, cc)) {
    int d[8];
    #pragma unroll
    for (int q = 0; q < 8; q++) d[q] = tiles[q] << 3;
    int spare = j - d[x];
    for (int q = 0; q < x; q++) { int s = CAP5 - d[q]; if (s > 0) spare += s; }
    bool found = false;
    for (int xs = 0; xs < 8; xs++) {
      int ov = d[xs] - CAP5;
      if (ov <= 0) continue;
      if (spare < ov) { dec5(xs, CAP5 + spare, tiles, e, t, cc); found = true; break; }
      spare -= ov;
    }
    if (!found) return;
  }
  int row0 = hdr[H_OFFS + e] + (t << 7);
  int nrows = hdr[H_OFFS + e + 1] - row0; if (nrows > 128) nrows = 128;
  int n0 = cc << 7;   // out-col base (0..1023 step 128)

  __shared__ __align__(16) ushort_t As[4096];
  __shared__ __align__(16) ushort_t Bs[4096];
  __shared__ int rowslot[128];
  __shared__ float roww[128];

  int tt = threadIdx.x;
  if (tt < 128) {
    int sl = (tt < nrows) ? perm[row0 + tt] : -1;
    rowslot[tt] = sl;
    roww[tt] = (sl >= 0) ? wts[sl] : 0.f;
  }

  int lane = tt & 63, wave = tt >> 6;
  const ushort_t* wbase = wdn + (size_t)e * DIM * HID;

  const ushort_t *gpL, *gpH; ushort_t* lb;
  int sp = (wave & 1) << 1;
  if (wave < 2) {
    int rL = (lane < nrows) ? lane : 0;
    int rH = (64 + lane < nrows) ? 64 + lane : 0;
    int slL = perm[row0 + rL];
    int slH = perm[row0 + rH];
    gpL = h + (size_t)slL * HID;
    gpH = h + (size_t)slH * HID;
    lb = As;
  } else {
    gpL = wbase + (size_t)(n0 + lane) * HID;
    gpH = wbase + (size_t)(n0 + 64 + lane) * HID;
    lb = Bs;
  }

  floatx4 acc[4][4];
  #pragma unroll
  for (int a = 0; a < 4; a++)
  #pragma unroll
  for (int b = 0; b < 4; b++) acc[a][b] = (floatx4){0.f, 0.f, 0.f, 0.f};

  int quad = lane >> 4, l15 = lane & 15;
  int wr64 = (wave >> 1) << 6;
  int wc = wave & 1;
  int abyte = quad * 2048 + (wr64 + l15) * 16;
  int bbyte = quad * 2048 + ((wc << 6) + l15) * 16;

  for (int kb = 0; kb < HID / 32; ++kb) {
    gld16(gpL + sp * 8,     lb + sp * 1024);
    gld16(gpL + sp * 8 + 8, lb + sp * 1024 + 1024);
    gld16(gpH + sp * 8,     lb + sp * 1024 + 512);
    gld16(gpH + sp * 8 + 8, lb + sp * 1024 + 1536);
    gpL += 32; gpH += 32;
    __syncthreads();
    bf16x8 af0 = *(const bf16x8*)((const char*)As + abyte);
    bf16x8 af1 = *(const bf16x8*)((const char*)As + abyte + 256);
    bf16x8 af2 = *(const bf16x8*)((const char*)As + abyte + 512);
    bf16x8 af3 = *(const bf16x8*)((const char*)As + abyte + 768);
    #pragma unroll
    for (int ct = 0; ct < 4; ++ct) {
      bf16x8 bfr = *(const bf16x8*)((const char*)Bs + bbyte + ct * 256);
      acc[0][ct] = __builtin_amdgcn_mfma_f32_16x16x32_bf16(af0, bfr, acc[0][ct], 0, 0, 0);
      acc[1][ct] = __builtin_amdgcn_mfma_f32_16x16x32_bf16(af1, bfr, acc[1][ct], 0, 0, 0);
      acc[2][ct] = __builtin_amdgcn_mfma_f32_16x16x32_bf16(af2, bfr, acc[2][ct], 0, 0, 0);
      acc[3][ct] = __builtin_amdgcn_mfma_f32_16x16x32_bf16(af3, bfr, acc[3][ct], 0, 0, 0);
    }
    __syncthreads();
  }

  #pragma unroll
  for (int rt = 0; rt < 4; ++rt)
  #pragma unroll
  for (int ct = 0; ct < 4; ++ct) {
    floatx4 d = acc[rt][ct];
    #pragma unroll
    for (int jj = 0; jj < 4; ++jj) {
      int r = wr64 + rt * 16 + quad * 4 + jj;
      int slot = rowslot[r];
      if (slot >= 0)
        dwn[(size_t)slot * DIM + n0 + (wc << 6) + ct * 16 + l15] = f2bf(d[jj] * roww[r]);
    }
  }
}

// out = x + dwn[2t] + dwn[2t+1]  (fp32 out, bf16 dwn)
__global__ __launch_bounds__(256) void k6_combine(
    const float* __restrict__ x, const ushort_t* __restrict__ dwn,
    float* __restrict__ out)
{
  int token = blockIdx.x, t = threadIdx.x;
  float4 xa = ((const float4*)(x + (size_t)token * DIM))[t];
  ushort4 a = ((const ushort4*)(dwn + (size_t)(2 * token)     * DIM))[t];
  ushort4 b = ((const ushort4*)(dwn + (size_t)(2 * token + 1) * DIM))[t];
  union { unsigned int i; float f; } c0, c1, c2, c3, d0, d1, d2, d3;
  c0.i = (u32)a.x << 16; c1.i = (u32)a.y << 16; c2.i = (u32)a.z << 16; c3.i = (u32)a.w << 16;
  d0.i = (u32)b.x << 16; d1.i = (u32)b.y << 16; d2.i = (u32)b.z << 16; d3.i = (u32)b.w << 16;
  float4 o;
  o.x = xa.x + c0.f + d0.f;
  o.y = xa.y + c1.f + d1.f;
  o.z = xa.z + c2.f + d2.f;
  o.w = xa.w + c3.f + d3.f;
  ((float4*)(out + (size_t)token * DIM))[t] = o;
}

extern "C" void kernel_launch(void* const* d_in, const int* in_sizes, int n_in,
                              void* d_out, int out_size, void* d_ws, size_t ws_size,
                              hipStream_t stream)
{
  const float* x   = (const float*)d_in[0];
  const float* sc  = (const float*)d_in[1];
  const float* wr  = (const float*)d_in[2];
  const float* wup = (const float*)d_in[3];
  const float* wdn = (const float*)d_in[4];
  float* out = (float*)d_out;

  char* ws = (char*)d_ws;
  int*      hdr  = (int*)ws;                          // 16 KB
  int*      ids  = (int*)(ws + 16384);                // [NSLOT]
  float*    wts  = (float*)(ws + 147456);             // [NSLOT]
  int*      perm = (int*)(ws + 278528);               // [NSLOT]
  ushort_t* xn   = (ushort_t*)(ws + 409600);          // 32 MB  [dead after k4]
  ushort_t* wupb = (ushort_t*)(ws + 33964032ull);     // 64 MB  [dead after k4]
  ushort_t* h    = (ushort_t*)(ws + 101072896ull);    // 128 MB
  ushort_t* wdnb = (ushort_t*)(ws + 67518464ull);     // 32 MB, upper half of wupb region
  ushort_t* dwn  = (ushort_t*)(ws + 409600);          // 64 MB, overlays xn + lower wupb
  // peak ws: 101072896 + 128MB = 235,290,624 B (~224 MiB)

  k0_init<<<1, 64, 0, stream>>>(hdr);
  kconv<<<4096, 256, 0, stream>>>(wup, wupb, NEXP * 2 * HID * DIM / 4);
  k1_norm_router<<<MTOK, 256, 0, stream>>>(x, sc, wr, xn, ids, wts, hdr);
  k2_scan<<<1, 64, 0, stream>>>(hdr);
  k3_scatter<<<NSLOT / 256, 256, 0, stream>>>(ids, hdr, perm);
  k4_up<<<GRID4, 256, 0, stream>>>(xn, wupb, hdr, perm, h);
  kconv<<<4096, 256, 0, stream>>>(wdn, wdnb, NEXP * DIM * HID / 4);
  k5_down<<<GRID5, 256, 0, stream>>>(h, wdnb, hdr, perm, wts, dwn);
  k6_combine<<<MTOK, 256, 0, stream>>>(x, dwn, out);
}